// Round 6
// baseline (100.402 us; speedup 1.0000x reference)
//
#include <hip/hip_runtime.h>
#include <hip/hip_bf16.h>

#define NSEQ   192
#define PADV   -1000.0f
#define NEGINF -1.0e30f

typedef __bf16 bf16x8 __attribute__((ext_vector_type(8)));
typedef float  f32x4  __attribute__((ext_vector_type(4)));

__device__ __forceinline__ void glds16(const void* g, void* l) {
  __builtin_amdgcn_global_load_lds(
      (const __attribute__((address_space(1))) unsigned int*)g,
      (__attribute__((address_space(3))) unsigned int*)l, 16, 0, 0);
}

#define MFMA16(a, b, c) __builtin_amdgcn_mfma_f32_16x16x32_bf16((a), (b), (c), 0, 0, 0)

// ---------------------------------------------------------------------------
// prep_pack: repack weights into bf16 MFMA fragment order.
//   frag: lane l elem e holds M[k=(l>>4)*8+e][h=l&15+16*q]  (B-frag of M, and
//   equally the A-frag of M^T). W1cp/W2p slices padded to 12 frags (2 zero)
//   so staging is uniform 3 frags/wave.
// Region 1: W1ab = [W1a|W1b] (24 kk x 20 frag)      245760 elems
// Region 2: W1c  padded      (24 kk x 12 frag)      147456 elems
// Region 3: W2   padded      ( 5 s  x 12 frag)       30720 elems
// ---------------------------------------------------------------------------
__global__ __launch_bounds__(256) void prep_pack(const float* __restrict__ W1,
                                                 const float* __restrict__ W2,
                                                 __bf16* __restrict__ W1abp,
                                                 __bf16* __restrict__ W1cp,
                                                 __bf16* __restrict__ W2p) {
  int idx = blockIdx.x * 256 + threadIdx.x;   // grid 1656*256 == 423936 exact
  if (idx < 245760) {
    int e = idx & 7, l = (idx >> 3) & 63, t = idx >> 9;
    int ct = t % 20, kk = t / 20;             // kk 0..23
    int k = kk * 32 + ((l >> 4) << 3) + e;    // 0..767
    int hp = ct * 16 + (l & 15);              // 0..319
    int col = (hp < 160) ? hp : hp - 160;
    int rbase = (hp < 160) ? 0 : 768;
    float v = (col < 150) ? W1[(size_t)(rbase + k) * 150 + col] : 0.f;
    W1abp[idx] = (__bf16)v;
  } else if (idx < 393216) {
    int j = idx - 245760;
    int kk = j / 6144, rem = j % 6144;
    int q = rem >> 9, l = (rem >> 3) & 63, e = rem & 7;
    int k = kk * 32 + ((l >> 4) << 3) + e;
    int h = q * 16 + (l & 15);
    float v = (q < 10 && h < 150) ? W1[(size_t)(1536 + k) * 150 + h] : 0.f;
    W1cp[j] = (__bf16)v;
  } else {
    int j = idx - 393216;                     // < 30720
    int s = j / 6144, rem = j % 6144;
    int q = rem >> 9, l = (rem >> 3) & 63, e = rem & 7;
    int k = s * 32 + ((l >> 4) << 3) + e;
    int h = q * 16 + (l & 15);
    float v = (q < 10 && k < 150 && h < 150) ? W2[(size_t)k * 150 + h] : 0.f;
    W2p[j] = (__bf16)v;
  }
}

// ---------------------------------------------------------------------------
// prep_gemm: A12[1536][320] += E @ [W1a|W1b], K split 8 ways (f32 atomics).
// ---------------------------------------------------------------------------
__global__ __launch_bounds__(256) void prep_gemm(const float* __restrict__ E,
                                                 const __bf16* __restrict__ W1abp,
                                                 float* __restrict__ A12) {
  int tid = threadIdx.x;
  int w = tid >> 6, l = tid & 63, m = l & 15, kg = l >> 4;
  int mt = blockIdx.x >> 3;                   // 0..95
  int c  = blockIdx.x & 7;                    // K-chunk 0..7
  const float* ep = E + (size_t)(mt * 16 + m) * 768 + c * 96;

  f32x4 acc[5];
#pragma unroll
  for (int u = 0; u < 5; ++u) acc[u] = (f32x4){0.f, 0.f, 0.f, 0.f};

#pragma unroll
  for (int kk = 0; kk < 3; ++kk) {
    int k = kk * 32 + kg * 8;
    f32x4 x0 = *(const f32x4*)(ep + k);
    f32x4 x1 = *(const f32x4*)(ep + k + 4);
    bf16x8 af;
#pragma unroll
    for (int e = 0; e < 4; ++e) { af[e] = (__bf16)x0[e]; af[e + 4] = (__bf16)x1[e]; }
    const bf16x8* wp = (const bf16x8*)W1abp + (size_t)(((c * 3 + kk) * 20) + w * 5) * 64 + l;
#pragma unroll
    for (int u = 0; u < 5; ++u)
      acc[u] = MFMA16(af, wp[u * 64], acc[u]);
  }
#pragma unroll
  for (int u = 0; u < 5; ++u)
#pragma unroll
    for (int r = 0; r < 4; ++r)
      atomicAdd(&A12[(size_t)(mt * 16 + kg * 4 + r) * 320 + (w * 5 + u) * 16 + m], acc[u][r]);
}

// ---------------------------------------------------------------------------
// pair_mlp: block = 16i x 16j tile (624 blocks). 4 waves; wave w owns j-cols
// {w*4..w*4+3}. GEMM1 SWAPPED: C1[h][pair] = W1c^T(A) x pairfrags(B) so each
// W-frag read feeds 4 MFMAs. BK=32 staged slices (12 frags, 3 glds/wave,
// vmcnt(3) + raw barriers). e_i/e_j bf16 in LDS, chunk-XOR swizzled.
// GEMM2: h1 via wave-private LDS, 2 passes x 2 j-cols, W2 stream-dbuf.
// ---------------------------------------------------------------------------
__global__ __launch_bounds__(256, 2) void pair_mlp(
    const float* __restrict__ E, const float* __restrict__ A12,
    const __bf16* __restrict__ W1cp, const __bf16* __restrict__ W2p,
    const float* __restrict__ b1, const float* __restrict__ b2,
    const float* __restrict__ W3, const float* __restrict__ b3,
    float* __restrict__ out) {
  __shared__ alignas(16) char pool[73728];
  __bf16* Wb  = (__bf16*)pool;          // [2][12][512] bf16 frags (24 KB)
  char*   eib = pool + 24576;           // 16 rows x 96 chunks(16B), swizzled
  char*   ejb = pool + 49152;           // 16 rows x 96 chunks(16B), swizzled
  char*   h1b = pool + 24576;           // GEMM2: [4w][2pt][16 pair][336B]

  const int tid = threadIdx.x;
  const int w = tid >> 6, l = tid & 63;
  const int m = l & 15, kg = l >> 4;

  // XCD-aware bijective swizzle (624 == 8*78), then tri decode
  int bid = blockIdx.x;
  int blk = (bid & 7) * 78 + (bid >> 3);
  int b = blk / 78, r0 = blk - b * 78;
  int it = (int)((sqrtf(8.f * (float)r0 + 1.f) - 1.f) * 0.5f);
  while (it * (it + 1) / 2 > r0) --it;
  while ((it + 1) * (it + 2) / 2 <= r0) ++it;
  int jt = r0 - it * (it + 1) / 2;      // 0..it

  const int ibase = b * NSEQ + it * 16;
  const int jbase = b * NSEQ + jt * 16;

  // ---- stage W1c slice 0 (oldest in vm queue) ----
#pragma unroll
  for (int q = 0; q < 3; ++q)
    glds16(W1cp + (size_t)(w * 3 + q) * 512 + l * 8, Wb + (w * 3 + q) * 512);

  // ---- stage e_i and e_j as bf16, chunk-XOR swizzled ----
  {
    int r = tid >> 4, c0 = tid & 15;
    const float* si = E + (size_t)(ibase + r) * 768;
    const float* sj = E + (size_t)(jbase + r) * 768;
#pragma unroll
    for (int p = 0; p < 6; ++p) {
      int c = c0 + 16 * p;
      int cs = c ^ (r & 7);             // source chunk for dest chunk c
      f32x4 a0 = *(const f32x4*)(si + cs * 8);
      f32x4 a1 = *(const f32x4*)(si + cs * 8 + 4);
      f32x4 b0 = *(const f32x4*)(sj + cs * 8);
      f32x4 b1q = *(const f32x4*)(sj + cs * 8 + 4);
      bf16x8 vi, vj;
#pragma unroll
      for (int e = 0; e < 4; ++e) {
        vi[e] = (__bf16)a0[e]; vi[e + 4] = (__bf16)a1[e];
        vj[e] = (__bf16)b0[e]; vj[e + 4] = (__bf16)b1q[e];
      }
      *(bf16x8*)(eib + r * 1536 + c * 16) = vi;
      *(bf16x8*)(ejb + r * 1536 + c * 16) = vj;
    }
  }

  // ---- acc1 init: C1[h][pair] = A1[i(pair)][h] + A2[j(pt)][h] + b1[h] ----
  // lane (kg,m): h = ct*16 + kg*4 + r, pair col = m  ->  A1 row = ibase+m
  f32x4 acc1[10][4];
#pragma unroll
  for (int ct = 0; ct < 10; ++ct) {
    f32x4 a1v = *(const f32x4*)(A12 + (size_t)(ibase + m) * 320 + ct * 16 + kg * 4);
    f32x4 b1v;
#pragma unroll
    for (int r = 0; r < 4; ++r) {
      int h = ct * 16 + kg * 4 + r;
      b1v[r] = (h < 150) ? b1[h] : 0.f;
    }
#pragma unroll
    for (int pt = 0; pt < 4; ++pt) {
      f32x4 a2v = *(const f32x4*)(A12 + (size_t)(jbase + w * 4 + pt) * 320 + 160 + ct * 16 + kg * 4);
#pragma unroll
      for (int r = 0; r < 4; ++r) acc1[ct][pt][r] = a1v[r] + a2v[r] + b1v[r];
    }
  }

  __syncthreads();   // e-stage visible to all waves (drains glds(0) too)

  // ---- GEMM1: 24 k-steps of K=32 ----
  for (int kk = 0; kk < 24; ++kk) {
    if (kk < 23) {
#pragma unroll
      for (int q = 0; q < 3; ++q)
        glds16(W1cp + ((size_t)(kk + 1) * 12 + w * 3 + q) * 512 + l * 8,
               Wb + (((kk + 1) & 1) * 12 + w * 3 + q) * 512);
      asm volatile("s_waitcnt vmcnt(3)" ::: "memory");
    } else {
      asm volatile("s_waitcnt vmcnt(0)" ::: "memory");
    }
    __builtin_amdgcn_s_barrier();

    const __bf16* wbuf = Wb + (kk & 1) * 6144;
    int cbase = kk * 4 + kg;
    bf16x8 eiv = *(const bf16x8*)(eib + m * 1536 + (cbase ^ (m & 7)) * 16);
    float eif[8];
#pragma unroll
    for (int e = 0; e < 8; ++e) eif[e] = (float)eiv[e];
    bf16x8 pf[4];
#pragma unroll
    for (int pt = 0; pt < 4; ++pt) {
      int jr = w * 4 + pt;
      bf16x8 ejv = *(const bf16x8*)(ejb + jr * 1536 + (cbase ^ (jr & 7)) * 16);
#pragma unroll
      for (int e = 0; e < 8; ++e)
        pf[pt][e] = (__bf16)(eif[e] * (float)ejv[e]);
    }
    __builtin_amdgcn_s_setprio(1);
#pragma unroll
    for (int ct = 0; ct < 10; ++ct) {
      bf16x8 wf = *(const bf16x8*)(wbuf + ct * 512 + l * 8);
#pragma unroll
      for (int pt = 0; pt < 4; ++pt)
        acc1[ct][pt] = MFMA16(wf, pf[pt], acc1[ct][pt]);
    }
    __builtin_amdgcn_s_setprio(0);
    __builtin_amdgcn_s_barrier();
  }

  // ---- h1 -> wave-private LDS (relu, bf16), one pt-slot ----
  auto write_h1 = [&](int ptL, int pt) {
    char* hb = h1b + w * 10752 + ptL * 5376 + m * 336;
#pragma unroll
    for (int ct = 0; ct < 10; ++ct) {
      union { __bf16 h[4]; unsigned u[2]; } cv;
      cv.h[0] = (__bf16)fmaxf(acc1[ct][pt][0], 0.f);
      cv.h[1] = (__bf16)fmaxf(acc1[ct][pt][1], 0.f);
      cv.h[2] = (__bf16)fmaxf(acc1[ct][pt][2], 0.f);
      cv.h[3] = (__bf16)fmaxf(acc1[ct][pt][3], 0.f);
      *(unsigned*)(hb + ct * 32 + kg * 8)     = cv.u[0];
      *(unsigned*)(hb + ct * 32 + kg * 8 + 4) = cv.u[1];
    }
  };
  write_h1(0, 0);
  write_h1(1, 1);

  // per-lane W3/b2 at h2 = ct*16 + m (used by both passes)
  float w3v[10], b2v[10];
#pragma unroll
  for (int ct = 0; ct < 10; ++ct) {
    int h = ct * 16 + m;
    w3v[ct] = (h < 150) ? W3[h] : 0.f;
    b2v[ct] = (h < 150) ? b2[h] : 0.f;
  }
  float b3v = b3[0];

  // ---- GEMM2: stage W2 slice 0; 10 pipelined steps (2 passes x 5) ----
#pragma unroll
  for (int q = 0; q < 3; ++q)
    glds16(W2p + (size_t)(w * 3 + q) * 512 + l * 8, Wb + (w * 3 + q) * 512);

  f32x4 acc2[10][2];
#pragma unroll
  for (int ct = 0; ct < 10; ++ct) {
    acc2[ct][0] = (f32x4){0.f, 0.f, 0.f, 0.f};
    acc2[ct][1] = (f32x4){0.f, 0.f, 0.f, 0.f};
  }

  for (int skk = 0; skk < 10; ++skk) {
    int s = (skk >= 5) ? skk - 5 : skk;
    if (skk == 5) { write_h1(0, 2); write_h1(1, 3); }
    if (skk < 9) {
      int n = skk + 1;
      int sl = (n >= 5) ? n - 5 : n;
#pragma unroll
      for (int q = 0; q < 3; ++q)
        glds16(W2p + ((size_t)sl * 12 + w * 3 + q) * 512 + l * 8,
               Wb + ((n & 1) * 12 + w * 3 + q) * 512);
      asm volatile("s_waitcnt vmcnt(3)" ::: "memory");
    } else {
      asm volatile("s_waitcnt vmcnt(0)" ::: "memory");
    }
    __builtin_amdgcn_s_barrier();

    const __bf16* wbuf = Wb + (skk & 1) * 6144;
    bf16x8 af0 = *(const bf16x8*)(h1b + w * 10752 +        m * 336 + s * 64 + kg * 16);
    bf16x8 af1 = *(const bf16x8*)(h1b + w * 10752 + 5376 + m * 336 + s * 64 + kg * 16);
    __builtin_amdgcn_s_setprio(1);
#pragma unroll
    for (int ct = 0; ct < 10; ++ct) {
      bf16x8 wf = *(const bf16x8*)(wbuf + ct * 512 + l * 8);
      acc2[ct][0] = MFMA16(af0, wf, acc2[ct][0]);
      acc2[ct][1] = MFMA16(af1, wf, acc2[ct][1]);
    }
    __builtin_amdgcn_s_setprio(0);

    if (s == 4) {   // pass epilogue: fold + store, reset acc2
      int pass = skk / 5;
#pragma unroll
      for (int ptL = 0; ptL < 2; ++ptL) {
        float part[4] = {0.f, 0.f, 0.f, 0.f};
#pragma unroll
        for (int ct = 0; ct < 10; ++ct)
#pragma unroll
          for (int r = 0; r < 4; ++r)
            part[r] += fmaxf(acc2[ct][ptL][r] + b2v[ct], 0.f) * w3v[ct];
#pragma unroll
        for (int off = 8; off >= 1; off >>= 1)
#pragma unroll
          for (int r = 0; r < 4; ++r) part[r] += __shfl_xor(part[r], off, 16);
        int jl = jt * 16 + w * 4 + pass * 2 + ptL;
#pragma unroll
        for (int r = 0; r < 4; ++r) {
          if (m == r) {
            int il = it * 16 + kg * 4 + r;
            if (jl < il)
              out[(size_t)(b * NSEQ + il) * NSEQ + jl] = part[r] + b3v;
          }
        }
#pragma unroll
        for (int ct = 0; ct < 10; ++ct)
          acc2[ct][ptL] = (f32x4){0.f, 0.f, 0.f, 0.f};
      }
    }
    __builtin_amdgcn_s_barrier();
  }
}

// ---------------------------------------------------------------------------
// softmax: 4 (b,i)-rows per block, one wave each.
// ---------------------------------------------------------------------------
__global__ __launch_bounds__(256) void softmax_rows(float* __restrict__ out) {
  int w = threadIdx.x >> 6, l = threadIdx.x & 63;
  int blk = blockIdx.x * 4 + w;   // 0..1535 = b*192+i
  int i = blk % NSEQ;
  size_t base = (size_t)blk * NSEQ;
  float v[3];
  float mx = NEGINF;
#pragma unroll
  for (int t = 0; t < 3; ++t) {
    int j = l + 64 * t;
    float x = (j < i) ? out[base + j] : (j == i ? 0.f : NEGINF);
    v[t] = x;
    mx = fmaxf(mx, x);
  }
#pragma unroll
  for (int off = 32; off >= 1; off >>= 1) mx = fmaxf(mx, __shfl_xor(mx, off, 64));
  float s = 0.f;
#pragma unroll
  for (int t = 0; t < 3; ++t) s += __expf(v[t] - mx);
#pragma unroll
  for (int off = 32; off >= 1; off >>= 1) s += __shfl_xor(s, off, 64);
  float inv = 1.0f / s;
#pragma unroll
  for (int t = 0; t < 3; ++t) {
    int j = l + 64 * t;
    out[base + j] = (j <= i) ? __expf(v[t] - mx) * inv : PADV;
  }
}

// ---------------------------------------------------------------------------
extern "C" void kernel_launch(void* const* d_in, const int* in_sizes, int n_in,
                              void* d_out, int out_size, void* d_ws, size_t ws_size,
                              hipStream_t stream) {
  const float* E  = (const float*)d_in[0];
  const float* W1 = (const float*)d_in[1];
  const float* b1 = (const float*)d_in[2];
  const float* W2 = (const float*)d_in[3];
  const float* b2 = (const float*)d_in[4];
  const float* W3 = (const float*)d_in[5];
  const float* b3 = (const float*)d_in[6];
  float* out = (float*)d_out;

  char* ws = (char*)d_ws;
  float*  A12   = (float*)(ws);                 // 1,966,080 B
  __bf16* W1abp = (__bf16*)(ws + 1966080);      //   491,520 B
  __bf16* W1cp  = (__bf16*)(ws + 2457600);      //   294,912 B (12-frag padded)
  __bf16* W2p   = (__bf16*)(ws + 2752512);      //    61,440 B (12-frag padded)

  hipMemsetAsync(A12, 0, 1966080, stream);
  prep_pack<<<1656, 256, 0, stream>>>(W1, W2, W1abp, W1cp, W2p);
  prep_gemm<<<768, 256, 0, stream>>>(E, W1abp, A12);
  pair_mlp<<<624, 256, 0, stream>>>(E, A12, W1cp, W2p, b1, b2, W3, b3, out);
  softmax_rows<<<384, 256, 0, stream>>>(out);
}

// Round 7
// 100.325 us; speedup vs baseline: 1.0008x; 1.0008x over previous
//
#include <hip/hip_runtime.h>
#include <hip/hip_bf16.h>

#define NSEQ   192
#define PADV   -1000.0f
#define NEGINF -1.0e30f

typedef __bf16 bf16x8 __attribute__((ext_vector_type(8)));
typedef float  f32x4  __attribute__((ext_vector_type(4)));

__device__ __forceinline__ void glds16(const void* g, void* l) {
  __builtin_amdgcn_global_load_lds(
      (const __attribute__((address_space(1))) unsigned int*)g,
      (__attribute__((address_space(3))) unsigned int*)l, 16, 0, 0);
}

#define MFMA16(a, b, c) __builtin_amdgcn_mfma_f32_16x16x32_bf16((a), (b), (c), 0, 0, 0)

// ---------------------------------------------------------------------------
// prep_pack: repack weights into bf16 MFMA fragment order (frag: lane l elem
// e holds M[k=(l>>4)*8+e][h=(l&15)+16q]); 12-frag padded slices. Extra tail:
// b1p[160] zero-padded f32.
// ---------------------------------------------------------------------------
__global__ __launch_bounds__(256) void prep_pack(const float* __restrict__ W1,
                                                 const float* __restrict__ W2,
                                                 const float* __restrict__ b1,
                                                 __bf16* __restrict__ W1abp,
                                                 __bf16* __restrict__ W1cp,
                                                 __bf16* __restrict__ W2p,
                                                 float* __restrict__ b1p) {
  int idx = blockIdx.x * 256 + threadIdx.x;   // grid 1657*256
  if (idx < 245760) {
    int e = idx & 7, l = (idx >> 3) & 63, t = idx >> 9;
    int ct = t % 20, kk = t / 20;             // kk 0..23
    int k = kk * 32 + ((l >> 4) << 3) + e;    // 0..767
    int hp = ct * 16 + (l & 15);              // 0..319
    int col = (hp < 160) ? hp : hp - 160;
    int rbase = (hp < 160) ? 0 : 768;
    float v = (col < 150) ? W1[(size_t)(rbase + k) * 150 + col] : 0.f;
    W1abp[idx] = (__bf16)v;
  } else if (idx < 393216) {
    int j = idx - 245760;
    int kk = j / 6144, rem = j % 6144;
    int q = rem >> 9, l = (rem >> 3) & 63, e = rem & 7;
    int k = kk * 32 + ((l >> 4) << 3) + e;
    int h = q * 16 + (l & 15);
    float v = (q < 10 && h < 150) ? W1[(size_t)(1536 + k) * 150 + h] : 0.f;
    W1cp[j] = (__bf16)v;
  } else if (idx < 423936) {
    int j = idx - 393216;                     // < 30720
    int s = j / 6144, rem = j % 6144;
    int q = rem >> 9, l = (rem >> 3) & 63, e = rem & 7;
    int k = s * 32 + ((l >> 4) << 3) + e;
    int h = q * 16 + (l & 15);
    float v = (q < 10 && k < 150 && h < 150) ? W2[(size_t)k * 150 + h] : 0.f;
    W2p[j] = (__bf16)v;
  } else if (idx < 424096) {
    int h = idx - 423936;
    b1p[h] = (h < 150) ? b1[h] : 0.f;
  }
}

// ---------------------------------------------------------------------------
// prep_gemm: A12[1536][320] += E @ [W1a|W1b], K split 8 ways (f32 atomics).
// ---------------------------------------------------------------------------
__global__ __launch_bounds__(256) void prep_gemm(const float* __restrict__ E,
                                                 const __bf16* __restrict__ W1abp,
                                                 float* __restrict__ A12) {
  int tid = threadIdx.x;
  int w = tid >> 6, l = tid & 63, m = l & 15, kg = l >> 4;
  int mt = blockIdx.x >> 3;                   // 0..95
  int c  = blockIdx.x & 7;                    // K-chunk 0..7
  const float* ep = E + (size_t)(mt * 16 + m) * 768 + c * 96;

  f32x4 acc[5];
#pragma unroll
  for (int u = 0; u < 5; ++u) acc[u] = (f32x4){0.f, 0.f, 0.f, 0.f};

#pragma unroll
  for (int kk = 0; kk < 3; ++kk) {
    int k = kk * 32 + kg * 8;
    f32x4 x0 = *(const f32x4*)(ep + k);
    f32x4 x1 = *(const f32x4*)(ep + k + 4);
    bf16x8 af;
#pragma unroll
    for (int e = 0; e < 4; ++e) { af[e] = (__bf16)x0[e]; af[e + 4] = (__bf16)x1[e]; }
    const bf16x8* wp = (const bf16x8*)W1abp + (size_t)(((c * 3 + kk) * 20) + w * 5) * 64 + l;
#pragma unroll
    for (int u = 0; u < 5; ++u)
      acc[u] = MFMA16(af, wp[u * 64], acc[u]);
  }
#pragma unroll
  for (int u = 0; u < 5; ++u)
#pragma unroll
    for (int r = 0; r < 4; ++r)
      atomicAdd(&A12[(size_t)(mt * 16 + kg * 4 + r) * 320 + (w * 5 + u) * 16 + m], acc[u][r]);
}

// ---------------------------------------------------------------------------
// pair_mlp: block = 16i x 16j tile, 512 threads / 8 waves, wave w owns j-cols
// {2w, 2w+1}. Same swapped GEMM1 (C1[h][pair]); small per-wave rounds (20
// MFMA) but 16 waves/CU (VGPR<=128 via launch_bounds(512,4)) for overlap.
// Staging waves w<6 (2 glds each) with per-wave counted vmcnt. GEMM2: h1 per
// pair (384B stride, XOR swizzle), W2 slice dbuf, 2 passes x 5 slices,
// epilogue = in-lane fold + 2 shfl_xor over kg.
// ---------------------------------------------------------------------------
__global__ __launch_bounds__(512, 4) void pair_mlp(
    const float* __restrict__ E, const float* __restrict__ A12,
    const __bf16* __restrict__ W1cp, const __bf16* __restrict__ W2p,
    const float* __restrict__ b1p, const float* __restrict__ b2,
    const float* __restrict__ W3, const float* __restrict__ b3,
    float* __restrict__ out) {
  __shared__ alignas(16) char pool[75648];
  // [0,24576)      Wb: GEMM1 W1c slice dbuf / GEMM2 W2 slice dbuf (2x12288)
  // [24576,49152)  eib: 16 rows x 96 chunks(16B) bf16, XOR-swizzled
  // [49152,73728)  ejb: 16 rows x 96 chunks(16B) bf16, XOR-swizzled
  // [24576,73728)  GEMM2: h1 = 8 waves x 16 pairs x 384B (XOR-swizzled)
  // [73728,75648)  bw: b2f[160], w3f[160] f32
  char* eib = pool + 24576;
  char* ejb = pool + 49152;

  const int tid = threadIdx.x;
  const int w = tid >> 6, l = tid & 63;
  const int m = l & 15, kg = l >> 4;
  const int jr0 = 2 * w, jr1 = 2 * w + 1;     // tile-local j rows of this wave

  // XCD-aware bijective swizzle (624 == 8*78), then tri decode
  int bid = blockIdx.x;
  int blk = (bid & 7) * 78 + (bid >> 3);
  int b = blk / 78, r0 = blk - b * 78;
  int it = (int)((sqrtf(8.f * (float)r0 + 1.f) - 1.f) * 0.5f);
  while (it * (it + 1) / 2 > r0) --it;
  while ((it + 1) * (it + 2) / 2 <= r0) ++it;
  int jt = r0 - it * (it + 1) / 2;            // 0..it

  const int ibase = b * NSEQ + it * 16;
  const int jbase = b * NSEQ + jt * 16;

  // ---- stage W1c slice 0 (waves 0..5, 2 frags each) ----
  if (w < 6) {
#pragma unroll
    for (int q = 0; q < 2; ++q)
      glds16(W1cp + (size_t)(2 * w + q) * 512 + l * 8,
             pool + (2 * w + q) * 1024 + l * 16);
  }

  // ---- stage e_i and e_j as bf16 (chunk-XOR swizzled), 3 slots/thread ----
#pragma unroll
  for (int q = 0; q < 3; ++q) {
    int t = tid + 512 * q;                    // 0..1535
    int r = t / 96, d = t - (t / 96) * 96;
    int sc = d ^ (r & 7);
    const float* si = E + (size_t)(ibase + r) * 768 + sc * 8;
    const float* sj = E + (size_t)(jbase + r) * 768 + sc * 8;
    f32x4 a0 = *(const f32x4*)(si);
    f32x4 a1 = *(const f32x4*)(si + 4);
    f32x4 c0 = *(const f32x4*)(sj);
    f32x4 c1 = *(const f32x4*)(sj + 4);
    bf16x8 vi, vj;
#pragma unroll
    for (int e = 0; e < 4; ++e) {
      vi[e] = (__bf16)a0[e]; vi[e + 4] = (__bf16)a1[e];
      vj[e] = (__bf16)c0[e]; vj[e + 4] = (__bf16)c1[e];
    }
    *(bf16x8*)(eib + r * 1536 + d * 16) = vi;
    *(bf16x8*)(ejb + r * 1536 + d * 16) = vj;
  }

  // ---- stage b2/W3 (padded) into bw ----
  if (tid < 160) {
    float* bwf = (float*)(pool + 73728);
    bwf[tid]       = (tid < 150) ? b2[tid] : 0.f;
    bwf[160 + tid] = (tid < 150) ? W3[tid] : 0.f;
  }
  float b3v = b3[0];

  // ---- acc1 init: C1[h][pair] = A1[i=m][h] + A2[j][h] + b1[h] ----
  f32x4 acc1[10][2];
#pragma unroll
  for (int ct = 0; ct < 10; ++ct) {
    f32x4 a1v = *(const f32x4*)(A12 + (size_t)(ibase + m) * 320 + ct * 16 + kg * 4);
    f32x4 b1v = *(const f32x4*)(b1p + ct * 16 + kg * 4);
#pragma unroll
    for (int pt = 0; pt < 2; ++pt) {
      f32x4 a2v = *(const f32x4*)(A12 + (size_t)(jbase + jr0 + pt) * 320 + 160 + ct * 16 + kg * 4);
      acc1[ct][pt] = a1v + a2v + b1v;
    }
  }

  __syncthreads();   // drains all prologue VM + DS

  // ---- GEMM1 compute for one K=32 step ----
  auto compute = [&](int kk) {
    const __bf16* wb = (const __bf16*)(pool + (kk & 1) * 12288);
    int cb = kk * 4 + kg;
    bf16x8 eiv = *(const bf16x8*)(eib + m * 1536 + ((cb ^ (m & 7)) << 4));
    bf16x8 ej0 = *(const bf16x8*)(ejb + jr0 * 1536 + ((cb ^ (jr0 & 7)) << 4));
    bf16x8 ej1 = *(const bf16x8*)(ejb + jr1 * 1536 + ((cb ^ (jr1 & 7)) << 4));
    bf16x8 pf0, pf1;
#pragma unroll
    for (int e = 0; e < 8; ++e) {
      float ei = (float)eiv[e];
      pf0[e] = (__bf16)(ei * (float)ej0[e]);
      pf1[e] = (__bf16)(ei * (float)ej1[e]);
    }
    __builtin_amdgcn_s_setprio(1);
#pragma unroll
    for (int ct = 0; ct < 10; ++ct) {
      bf16x8 wf = *(const bf16x8*)(wb + ct * 512 + l * 8);
      acc1[ct][0] = MFMA16(wf, pf0, acc1[ct][0]);
      acc1[ct][1] = MFMA16(wf, pf1, acc1[ct][1]);
    }
    __builtin_amdgcn_s_setprio(0);
  };

  // ---- GEMM1: iters 0..22 pipelined, 23 peeled ----
  for (int kk = 0; kk < 23; ++kk) {
    if (w < 6) {
#pragma unroll
      for (int q = 0; q < 2; ++q)
        glds16(W1cp + ((size_t)(kk + 1) * 12 + 2 * w + q) * 512 + l * 8,
               pool + ((kk + 1) & 1) * 12288 + (2 * w + q) * 1024 + l * 16);
      asm volatile("s_waitcnt vmcnt(2)" ::: "memory");
    }
    __builtin_amdgcn_s_barrier();
    compute(kk);
    __builtin_amdgcn_s_barrier();
  }
  if (w < 6) asm volatile("s_waitcnt vmcnt(0)" ::: "memory");
  __builtin_amdgcn_s_barrier();
  compute(23);
  __builtin_amdgcn_s_barrier();   // all eib/ejb reads done -> h1 may overwrite

  // ---- h1 write (relu, bf16): pair m, h-chunks XOR-swizzled, stride 384 ----
  char* hb = pool + 24576 + w * 6144;
  auto write_h1 = [&](int p) {
#pragma unroll
    for (int ct = 0; ct < 10; ++ct) {
      union { __bf16 h[4]; unsigned u[2]; } cv;
      cv.h[0] = (__bf16)fmaxf(acc1[ct][p][0], 0.f);
      cv.h[1] = (__bf16)fmaxf(acc1[ct][p][1], 0.f);
      cv.h[2] = (__bf16)fmaxf(acc1[ct][p][2], 0.f);
      cv.h[3] = (__bf16)fmaxf(acc1[ct][p][3], 0.f);
      int c = (2 * ct + (kg >> 1)) ^ (m & 7);
      char* dst = hb + m * 384 + c * 16 + (kg & 1) * 8;
      *(unsigned*)(dst)     = cv.u[0];
      *(unsigned*)(dst + 4) = cv.u[1];
    }
  };
  write_h1(0);
  if (w < 6) {
#pragma unroll
    for (int q = 0; q < 2; ++q)
      glds16(W2p + (size_t)(2 * w + q) * 512 + l * 8,
             pool + (2 * w + q) * 1024 + l * 16);
  }

  // ---- GEMM2: 10 rounds = 2 passes x 5 slices, W2 dbuf by round parity ----
  const float* bwp = (const float*)(pool + 73728);
  f32x4 acc2[10];
#pragma unroll
  for (int ct = 0; ct < 10; ++ct) acc2[ct] = (f32x4){0.f, 0.f, 0.f, 0.f};

  for (int rr = 0; rr < 10; ++rr) {
    int p = rr / 5, s = rr - p * 5;
    if (rr == 5) write_h1(1);
    if (rr < 9) {
      int ns = (rr + 1 >= 5) ? rr + 1 - 5 : rr + 1;
      if (w < 6) {
#pragma unroll
        for (int q = 0; q < 2; ++q)
          glds16(W2p + ((size_t)ns * 12 + 2 * w + q) * 512 + l * 8,
                 pool + ((rr + 1) & 1) * 12288 + (2 * w + q) * 1024 + l * 16);
        asm volatile("s_waitcnt vmcnt(2)" ::: "memory");
      }
    } else {
      if (w < 6) asm volatile("s_waitcnt vmcnt(0)" ::: "memory");
    }
    __builtin_amdgcn_s_barrier();

    const __bf16* wb2 = (const __bf16*)(pool + (rr & 1) * 12288);
    bf16x8 af = *(const bf16x8*)(hb + m * 384 + (((4 * s + kg) ^ (m & 7)) << 4));
    __builtin_amdgcn_s_setprio(1);
#pragma unroll
    for (int ct = 0; ct < 10; ++ct) {
      bf16x8 wf = *(const bf16x8*)(wb2 + ct * 512 + l * 8);
      acc2[ct] = MFMA16(wf, af, acc2[ct]);
    }
    __builtin_amdgcn_s_setprio(0);

    if (s == 4) {   // pass epilogue: fold + cross-kg reduce + store
      float sum = 0.f;
#pragma unroll
      for (int ct = 0; ct < 10; ++ct) {
        f32x4 b2q = *(const f32x4*)(bwp + ct * 16 + kg * 4);
        f32x4 w3q = *(const f32x4*)(bwp + 160 + ct * 16 + kg * 4);
#pragma unroll
        for (int r = 0; r < 4; ++r)
          sum += fmaxf(acc2[ct][r] + b2q[r], 0.f) * w3q[r];
      }
      sum += __shfl_xor(sum, 16, 64);
      sum += __shfl_xor(sum, 32, 64);
      if (kg == 0) {
        int il = it * 16 + m;
        int jl = jt * 16 + 2 * w + p;
        if (jl < il)
          out[(size_t)(b * NSEQ + il) * NSEQ + jl] = sum + b3v;
      }
#pragma unroll
      for (int ct = 0; ct < 10; ++ct) acc2[ct] = (f32x4){0.f, 0.f, 0.f, 0.f};
    }
    __builtin_amdgcn_s_barrier();
  }
}

// ---------------------------------------------------------------------------
// softmax: 4 (b,i)-rows per block, one wave each.
// ---------------------------------------------------------------------------
__global__ __launch_bounds__(256) void softmax_rows(float* __restrict__ out) {
  int w = threadIdx.x >> 6, l = threadIdx.x & 63;
  int blk = blockIdx.x * 4 + w;   // 0..1535 = b*192+i
  int i = blk % NSEQ;
  size_t base = (size_t)blk * NSEQ;
  float v[3];
  float mx = NEGINF;
#pragma unroll
  for (int t = 0; t < 3; ++t) {
    int j = l + 64 * t;
    float x = (j < i) ? out[base + j] : (j == i ? 0.f : NEGINF);
    v[t] = x;
    mx = fmaxf(mx, x);
  }
#pragma unroll
  for (int off = 32; off >= 1; off >>= 1) mx = fmaxf(mx, __shfl_xor(mx, off, 64));
  float s = 0.f;
#pragma unroll
  for (int t = 0; t < 3; ++t) s += __expf(v[t] - mx);
#pragma unroll
  for (int off = 32; off >= 1; off >>= 1) s += __shfl_xor(s, off, 64);
  float inv = 1.0f / s;
#pragma unroll
  for (int t = 0; t < 3; ++t) {
    int j = l + 64 * t;
    out[base + j] = (j <= i) ? __expf(v[t] - mx) * inv : PADV;
  }
}

// ---------------------------------------------------------------------------
extern "C" void kernel_launch(void* const* d_in, const int* in_sizes, int n_in,
                              void* d_out, int out_size, void* d_ws, size_t ws_size,
                              hipStream_t stream) {
  const float* E  = (const float*)d_in[0];
  const float* W1 = (const float*)d_in[1];
  const float* b1 = (const float*)d_in[2];
  const float* W2 = (const float*)d_in[3];
  const float* b2 = (const float*)d_in[4];
  const float* W3 = (const float*)d_in[5];
  const float* b3 = (const float*)d_in[6];
  float* out = (float*)d_out;

  char* ws = (char*)d_ws;
  float*  A12   = (float*)(ws);                 // 1,966,080 B
  __bf16* W1abp = (__bf16*)(ws + 1966080);      //   491,520 B
  __bf16* W1cp  = (__bf16*)(ws + 2457600);      //   294,912 B (12-frag padded)
  __bf16* W2p   = (__bf16*)(ws + 2752512);      //    61,440 B (12-frag padded)
  float*  b1p   = (float*)(ws + 2813952);       //       640 B

  hipMemsetAsync(A12, 0, 1966080, stream);
  prep_pack<<<1657, 256, 0, stream>>>(W1, W2, b1, W1abp, W1cp, W2p, b1p);
  prep_gemm<<<768, 256, 0, stream>>>(E, W1abp, A12);
  pair_mlp<<<624, 512, 0, stream>>>(E, A12, W1cp, W2p, b1p, b2, W3, b3, out);
  softmax_rows<<<384, 256, 0, stream>>>(out);
}